// Round 9
// baseline (86.221 us; speedup 1.0000x reference)
//
#include <hip/hip_runtime.h>

// NoisyTopExpertsPerItemRouter: G=32,S=1024,H=2048,E=64,K=2 (top-2)
// Outputs (concat, f32): idx (N*2) | w (N*2) | aux (1) | probs (N*64)
//
// Split-precision bf16 MFMA (R3+-proven numerics):
//   a = ah + 2^-8*am, w = wh + 2^-8*wm; logits = accM + 2^-8*accS
// R8: W staged per-block into LDS via global_load_lds (killed the 4x W
// fan-out; 130->86us). R9: BK=64 (16 barriers instead of 32, 2x compute
// per drain) + memset folded into prep (one fewer dispatch).

constexpr int GS    = 32768;
constexpr int EXPN  = 64;
constexpr int HID   = 2048;
constexpr int BM    = 64;          // rows per block (4 row-tiles x 16)
constexpr int KHALF = 1024;
constexpr int NSUB  = KHALF / 32;  // 32 sub-chunks (W-fragment granularity)
constexpr int NCH   = KHALF / 64;  // 16 chunks per wave (BK=64)
constexpr int BUFB  = 32768;       // staged W bytes per chunk (both halves)

typedef __attribute__((ext_vector_type(8))) short s16x8;
typedef __attribute__((ext_vector_type(4))) float f32x4;

#define AS_GLOBAL(p) ((const __attribute__((address_space(1))) void*)(p))
#define AS_LDS(p)    ((__attribute__((address_space(3))) void*)(p))

__device__ __forceinline__ void decomp8(float4 x0, float4 x1, s16x8& h, s16x8& m)
{
    float v[8] = {x0.x,x0.y,x0.z,x0.w,x1.x,x1.y,x1.z,x1.w};
    #pragma unroll
    for (int i = 0; i < 8; ++i) {
        union { float f; unsigned u; } a; a.f = v[i];
        unsigned hb = (a.u + 0x7fffu + ((a.u >> 16) & 1u)) >> 16;  // RNE bf16
        union { unsigned u; float f; } hf; hf.u = hb << 16;
        float r = (v[i] - hf.f) * 256.f;         // exact residual, scaled 2^8
        union { float f; unsigned u; } rb; rb.f = r;
        h[i] = (short)hb;
        m[i] = (short)(rb.u >> 16);
    }
}

// W fragments: frag f = cs*256 + nt*64 + lane encodes
//   expert e = nt*16 + (lane&15), k = cs*32 + (lane>>4)*8 + j (j=0..7)
__global__ __launch_bounds__(256)
void prep_kernel(const float* __restrict__ W, short* __restrict__ WhF,
                 short* __restrict__ WmF, float* __restrict__ ws)
{
    if (blockIdx.x == 0 && threadIdx.x < 2 * EXPN)
        ws[threadIdx.x] = 0.f;     // imp/cnt accumulators (replaces memset)

    const int t  = blockIdx.x * 256 + threadIdx.x;   // 0..16383
    const int cs = t >> 8;
    const int nt = (t >> 6) & 3;
    const int l  = t & 63;
    const int e  = nt * 16 + (l & 15);
    const int kb = cs * 32 + ((l >> 4) << 3);
    const float* p = W + (size_t)e * HID + kb;
    float4 x0 = *(const float4*)p;
    float4 x1 = *(const float4*)(p + 4);
    s16x8 h, m;
    decomp8(x0, x1, h, m);
    *(s16x8*)&WhF[(size_t)t * 8] = h;
    *(s16x8*)&WmF[(size_t)t * 8] = m;
}

__global__ __launch_bounds__(512, 2)   // 2 blocks/CU, VGPR cap 128 (R6 lesson)
void router_kernel(const float* __restrict__ tokens,
                   const float* __restrict__ noise,
                   const float* __restrict__ bias,
                   const short* __restrict__ WhF,
                   const short* __restrict__ WmF,
                   float* __restrict__ out,
                   float* __restrict__ ws)
{
    // 2 x 32KB W staging buffers; region reused post-barrier for lg+red.
    __shared__ __align__(16) char smem[2 * BUFB];

    const int tid  = threadIdx.x;
    const int lane = tid & 63;
    const int wv   = tid >> 6;      // 0..7
    const int mt   = wv & 3;        // row-tile
    const int kh   = wv >> 2;       // K half
    const int row0 = blockIdx.x * BM;

    // A source: lane -> row = lane&15 (of this tile's 16 rows),
    // k-slice = (lane>>4)*8 within each 32-wide sub-chunk of my K half
    const float* Ap = tokens
        + (size_t)(row0 + mt * 16 + (lane & 15)) * HID
        + kh * KHALF + ((lane >> 4) << 3);

    // stage chunk c's W (both halves, hi+mid, 2 sub-chunks) into buffer b.
    // Buffer layout (32KB), region r=0..31 (1KB each, fragment-linear):
    //   r = half*16 + sub*8 + hm*4 + nt
    // Wave wv stages regions 4wv..4wv+3; LDS dest = uniform base + lane*16.
    auto stage = [&](int b, int c) {
        char* base = smem + b * BUFB;
        #pragma unroll
        for (int i = 0; i < 4; ++i) {
            const int r    = wv * 4 + i;
            const int half = r >> 4;
            const int sub  = (r >> 3) & 1;
            const int hm   = (r >> 2) & 1;
            const int nt   = r & 3;
            const int cs   = half * NSUB + c * 2 + sub;
            const short* src = (hm ? WmF : WhF)
                + ((size_t)cs * 256 + nt * 64 + lane) * 8;
            __builtin_amdgcn_global_load_lds(AS_GLOBAL(src),
                                             AS_LDS(base + r * 1024), 16, 0, 0);
        }
    };

    f32x4 accM[4], accS[4];
    #pragma unroll
    for (int nt = 0; nt < 4; ++nt) { accM[nt] = (f32x4)0.f; accS[nt] = (f32x4)0.f; }

    // prologue: stage chunk 0, prefetch A chunk 0 (sub0: +0,+4; sub1: +32,+36)
    float4 aA0 = *(const float4*)(Ap);
    float4 aA1 = *(const float4*)(Ap + 4);
    float4 aA2 = *(const float4*)(Ap + 32);
    float4 aA3 = *(const float4*)(Ap + 36);
    float4 aB0, aB1, aB2, aB3;
    stage(0, 0);
    __syncthreads();   // drains staging vmcnt

#define CHUNK(A0, A1, A2, A3, N0, N1, N2, N3, c)                                   \
    {                                                                              \
        const int bc = (c) & 1;                                                    \
        if ((c) + 1 < NCH) {                                                       \
            stage(bc ^ 1, (c) + 1);                                                \
            N0 = *(const float4*)(Ap + ((c) + 1) * 64);                            \
            N1 = *(const float4*)(Ap + ((c) + 1) * 64 + 4);                        \
            N2 = *(const float4*)(Ap + ((c) + 1) * 64 + 32);                       \
            N3 = *(const float4*)(Ap + ((c) + 1) * 64 + 36);                       \
        }                                                                          \
        const char* wb = smem + bc * BUFB + kh * 16384;                            \
        s16x8 ah, am;                                                              \
        decomp8(A0, A1, ah, am);                                                   \
        _Pragma("unroll")                                                          \
        for (int nt = 0; nt < 4; ++nt) {                                           \
            s16x8 bh = *(const s16x8*)(wb + nt * 1024 + lane * 16);                \
            s16x8 bm = *(const s16x8*)(wb + 4096 + nt * 1024 + lane * 16);         \
            accM[nt] = __builtin_amdgcn_mfma_f32_16x16x32_bf16(ah, bh, accM[nt], 0, 0, 0); \
            accS[nt] = __builtin_amdgcn_mfma_f32_16x16x32_bf16(ah, bm, accS[nt], 0, 0, 0); \
            accS[nt] = __builtin_amdgcn_mfma_f32_16x16x32_bf16(am, bh, accS[nt], 0, 0, 0); \
        }                                                                          \
        decomp8(A2, A3, ah, am);                                                   \
        _Pragma("unroll")                                                          \
        for (int nt = 0; nt < 4; ++nt) {                                           \
            s16x8 bh = *(const s16x8*)(wb + 8192 + nt * 1024 + lane * 16);         \
            s16x8 bm = *(const s16x8*)(wb + 8192 + 4096 + nt * 1024 + lane * 16);  \
            accM[nt] = __builtin_amdgcn_mfma_f32_16x16x32_bf16(ah, bh, accM[nt], 0, 0, 0); \
            accS[nt] = __builtin_amdgcn_mfma_f32_16x16x32_bf16(ah, bm, accS[nt], 0, 0, 0); \
            accS[nt] = __builtin_amdgcn_mfma_f32_16x16x32_bf16(am, bh, accS[nt], 0, 0, 0); \
        }                                                                          \
        __syncthreads();  /* drains stage vmcnt; buffers swap safely */            \
    }

    for (int c = 0; c < NCH; c += 2) {
        CHUNK(aA0, aA1, aA2, aA3, aB0, aB1, aB2, aB3, c);
        CHUNK(aB0, aB1, aB2, aB3, aA0, aA1, aA2, aA3, c + 1);
    }
#undef CHUNK

    // ---- epilogue workspace aliases staging buffers (post-barrier safe) ----
    float (*lg)[EXPN + 1] = (float (*)[EXPN + 1])smem;
    float (*red)[EXPN]    = (float (*)[EXPN])(smem + BM * (EXPN + 1) * 4);

    // combine K halves; C/D layout: col=lane&15, row=(lane>>4)*4+reg [m89]
    if (kh == 0) {
        #pragma unroll
        for (int nt = 0; nt < 4; ++nt)
            #pragma unroll
            for (int r = 0; r < 4; ++r)
                lg[mt * 16 + (lane >> 4) * 4 + r][nt * 16 + (lane & 15)]
                    = accM[nt][r] + 0.00390625f * accS[nt][r];
    }
    __syncthreads();
    if (kh == 1) {
        #pragma unroll
        for (int nt = 0; nt < 4; ++nt)
            #pragma unroll
            for (int r = 0; r < 4; ++r)
                lg[mt * 16 + (lane >> 4) * 4 + r][nt * 16 + (lane & 15)]
                    += accM[nt][r] + 0.00390625f * accS[nt][r];
    }
    __syncthreads();

    // ---- per-row epilogue: 8 waves x 8 rows (proven R1-R8) ----
    float* out_idx   = out;
    float* out_w     = out + 2 * GS;
    float* out_probs = out + 4 * GS + 1;

    const float blane = bias[lane];
    float impL = 0.f, cntL = 0.f;

    for (int rr = 0; rr < 8; ++rr) {
        const int r = (wv << 3) + rr;
        const size_t row = (size_t)row0 + r;
        float v = lg[r][lane] + blane + noise[row * EXPN + lane];

        float m = v;
        #pragma unroll
        for (int off = 32; off >= 1; off >>= 1)
            m = fmaxf(m, __shfl_xor(m, off));
        float e = expf(v - m);
        float s = e;
        #pragma unroll
        for (int off = 32; off >= 1; off >>= 1)
            s += __shfl_xor(s, off);
        float p = e / s;

        out_probs[row * EXPN + lane] = p;
        impL += p;
        cntL += (p > 0.f) ? 1.f : 0.f;

        float v1 = p; int i1 = lane;
        #pragma unroll
        for (int off = 32; off >= 1; off >>= 1) {
            float ov = __shfl_xor(v1, off);
            int   oi = __shfl_xor(i1, off);
            if (ov > v1 || (ov == v1 && oi < i1)) { v1 = ov; i1 = oi; }
        }
        float v2 = (lane == i1) ? -1.f : p; int i2 = lane;
        #pragma unroll
        for (int off = 32; off >= 1; off >>= 1) {
            float ov = __shfl_xor(v2, off);
            int   oi = __shfl_xor(i2, off);
            if (ov > v2 || (ov == v2 && oi < i2)) { v2 = ov; i2 = oi; }
        }
        if (lane == 0) {
            float denom = v1 + v2 + 1e-9f;
            out_idx[row * 2 + 0] = (float)i1;
            out_idx[row * 2 + 1] = (float)i2;
            out_w[row * 2 + 0] = v1 / denom;
            out_w[row * 2 + 1] = v2 / denom;
        }
    }

    red[wv][lane]     = impL;
    red[8 + wv][lane] = cntL;
    __syncthreads();
    if (tid < EXPN) {
        float t1 = 0.f, t2 = 0.f;
        #pragma unroll
        for (int w = 0; w < 8; ++w) { t1 += red[w][tid]; t2 += red[8 + w][tid]; }
        atomicAdd(&ws[tid], t1);
        atomicAdd(&ws[EXPN + tid], t2);
    }
}

__global__ void aux_kernel(const float* __restrict__ ws, float* __restrict__ out)
{
    const int lane = threadIdx.x;  // 64 threads
    float x = ws[lane] * ws[EXPN + lane];   // importance * load
    float s = x;
    #pragma unroll
    for (int off = 32; off >= 1; off >>= 1)
        s += __shfl_xor(s, off);
    float mean = s * (1.f / 64.f);
    float d = x - mean;
    float ss = d * d;
    #pragma unroll
    for (int off = 32; off >= 1; off >>= 1)
        ss += __shfl_xor(ss, off);
    if (lane == 0)
        out[4 * GS] = 0.01f * (ss / 63.f);   // unbiased var * 0.01
}

extern "C" void kernel_launch(void* const* d_in, const int* in_sizes, int n_in,
                              void* d_out, int out_size, void* d_ws, size_t ws_size,
                              hipStream_t stream)
{
    const float* tokens = (const float*)d_in[0];
    const float* noise  = (const float*)d_in[1];
    const float* W      = (const float*)d_in[2];
    const float* bias   = (const float*)d_in[3];
    float* out = (float*)d_out;
    float* ws  = (float*)d_ws;

    // ws layout: [0..127] f32 imp/cnt accumulators | WhF (256KB) | WmF (256KB)
    short* WhF = (short*)(ws + 128);
    short* WmF = WhF + (size_t)EXPN * HID;

    prep_kernel<<<EXPN * HID / 8 / 256, 256, 0, stream>>>(W, WhF, WmF, ws);
    router_kernel<<<GS / BM, 512, 0, stream>>>(tokens, noise, bias, WhF, WmF,
                                               out, ws);
    aux_kernel<<<1, 64, 0, stream>>>(ws, out);
}

// Round 11
// 78.226 us; speedup vs baseline: 1.1022x; 1.1022x over previous
//
#include <hip/hip_runtime.h>

// NoisyTopExpertsPerItemRouter: G=32,S=1024,H=2048,E=64,K=2 (top-2)
// Outputs (concat, f32): idx (N*2) | w (N*2) | aux (1) | probs (N*64)
//
// bf16 MFMA with A-side split precision only (R10/R11):
//   a = ah + 2^-8*am (near-exact), w ~= wh (bf16 RNE, rel err <= 2^-9)
//   logits = accM(ah*wh) + 2^-8*accS(am*wh)
// R11: fix R10's smem-size bug (ternary evaluated to 20736 < needed 32768;
// OOB global_load_lds writes were dropped -> garbage odd-chunk logits ->
// aux blew threshold). Numerics of the W-mid drop are fine.

constexpr int GS    = 32768;
constexpr int EXPN  = 64;
constexpr int HID   = 2048;
constexpr int BM    = 64;          // rows per block (4 row-tiles x 16)
constexpr int KHALF = 1024;
constexpr int NSUB  = KHALF / 32;  // 32 sub-chunks (W-fragment granularity)
constexpr int NCH   = KHALF / 64;  // 16 chunks per wave (BK=64)
constexpr int BUFB  = 16384;       // staged W-hi bytes per chunk (both halves)

typedef __attribute__((ext_vector_type(8))) short s16x8;
typedef __attribute__((ext_vector_type(4))) float f32x4;

#define AS_GLOBAL(p) ((const __attribute__((address_space(1))) void*)(p))
#define AS_LDS(p)    ((__attribute__((address_space(3))) void*)(p))

__device__ __forceinline__ void decomp8(float4 x0, float4 x1, s16x8& h, s16x8& m)
{
    float v[8] = {x0.x,x0.y,x0.z,x0.w,x1.x,x1.y,x1.z,x1.w};
    #pragma unroll
    for (int i = 0; i < 8; ++i) {
        union { float f; unsigned u; } a; a.f = v[i];
        unsigned hb = (a.u + 0x7fffu + ((a.u >> 16) & 1u)) >> 16;  // RNE bf16
        union { unsigned u; float f; } hf; hf.u = hb << 16;
        float r = (v[i] - hf.f) * 256.f;         // exact residual, scaled 2^8
        union { float f; unsigned u; } rb; rb.f = r;
        h[i] = (short)hb;
        m[i] = (short)(rb.u >> 16);
    }
}

__device__ __forceinline__ unsigned short f2bf(float x) {
    union { float f; unsigned u; } v; v.f = x;
    return (unsigned short)((v.u + 0x7fffu + ((v.u >> 16) & 1u)) >> 16);  // RNE
}

// W-hi fragments: frag f = cs*256 + nt*64 + lane encodes
//   expert e = nt*16 + (lane&15), k = cs*32 + (lane>>4)*8 + j (j=0..7)
__global__ __launch_bounds__(256)
void prep_kernel(const float* __restrict__ W, short* __restrict__ WhF,
                 float* __restrict__ ws)
{
    if (blockIdx.x == 0 && threadIdx.x < 2 * EXPN)
        ws[threadIdx.x] = 0.f;     // imp/cnt accumulators (replaces memset)

    const int t  = blockIdx.x * 256 + threadIdx.x;   // 0..16383
    const int cs = t >> 8;
    const int nt = (t >> 6) & 3;
    const int l  = t & 63;
    const int e  = nt * 16 + (l & 15);
    const int kb = cs * 32 + ((l >> 4) << 3);
    const float* p = W + (size_t)e * HID + kb;
    float4 x0 = *(const float4*)p;
    float4 x1 = *(const float4*)(p + 4);
    float v[8] = {x0.x,x0.y,x0.z,x0.w,x1.x,x1.y,x1.z,x1.w};
    s16x8 h;
    #pragma unroll
    for (int i = 0; i < 8; ++i) h[i] = (short)f2bf(v[i]);
    *(s16x8*)&WhF[(size_t)t * 8] = h;
}

__global__ __launch_bounds__(512, 2)   // 2 blocks/CU, VGPR cap 128 (R6 lesson)
void router_kernel(const float* __restrict__ tokens,
                   const float* __restrict__ noise,
                   const float* __restrict__ bias,
                   const short* __restrict__ WhF,
                   float* __restrict__ out,
                   float* __restrict__ ws)
{
    // 2 x 16KB W staging buffers (32KB total). After the K-loop the region
    // is reused (post-barrier) for lg[64][65] (16.25KB) + red[16][64] (4KB).
    __shared__ __align__(16) char smem[2 * BUFB];

    const int tid  = threadIdx.x;
    const int lane = tid & 63;
    const int wv   = tid >> 6;      // 0..7
    const int mt   = wv & 3;        // row-tile
    const int kh   = wv >> 2;       // K half
    const int row0 = blockIdx.x * BM;

    // A source: lane -> row = lane&15 (of this tile's 16 rows),
    // k-slice = (lane>>4)*8 within each 32-wide sub-chunk of my K half
    const float* Ap = tokens
        + (size_t)(row0 + mt * 16 + (lane & 15)) * HID
        + kh * KHALF + ((lane >> 4) << 3);

    // stage chunk c's W-hi (both halves, 2 sub-chunks) into buffer b.
    // Buffer layout (16KB), region r=0..15 (1KB each, fragment-linear):
    //   r = half*8 + sub*4 + nt
    // Wave wv stages regions 2wv, 2wv+1; LDS dest = uniform base + lane*16.
    auto stage = [&](int b, int c) {
        char* base = smem + b * BUFB;
        #pragma unroll
        for (int i = 0; i < 2; ++i) {
            const int r    = wv * 2 + i;
            const int half = r >> 3;
            const int sub  = (r >> 2) & 1;
            const int nt   = r & 3;
            const int cs   = half * NSUB + c * 2 + sub;
            const short* src = WhF + ((size_t)cs * 256 + nt * 64 + lane) * 8;
            __builtin_amdgcn_global_load_lds(AS_GLOBAL(src),
                                             AS_LDS(base + r * 1024), 16, 0, 0);
        }
    };

    f32x4 accM[4], accS[4];
    #pragma unroll
    for (int nt = 0; nt < 4; ++nt) { accM[nt] = (f32x4)0.f; accS[nt] = (f32x4)0.f; }

    // prologue: stage chunk 0, prefetch A chunk 0 (sub0: +0,+4; sub1: +32,+36)
    float4 aA0 = *(const float4*)(Ap);
    float4 aA1 = *(const float4*)(Ap + 4);
    float4 aA2 = *(const float4*)(Ap + 32);
    float4 aA3 = *(const float4*)(Ap + 36);
    float4 aB0, aB1, aB2, aB3;
    stage(0, 0);
    __syncthreads();   // drains staging vmcnt

#define CHUNK(A0, A1, A2, A3, N0, N1, N2, N3, c)                                   \
    {                                                                              \
        const int bc = (c) & 1;                                                    \
        if ((c) + 1 < NCH) {                                                       \
            stage(bc ^ 1, (c) + 1);                                                \
            N0 = *(const float4*)(Ap + ((c) + 1) * 64);                            \
            N1 = *(const float4*)(Ap + ((c) + 1) * 64 + 4);                        \
            N2 = *(const float4*)(Ap + ((c) + 1) * 64 + 32);                       \
            N3 = *(const float4*)(Ap + ((c) + 1) * 64 + 36);                       \
        }                                                                          \
        const char* wb = smem + bc * BUFB + kh * 8192;                             \
        s16x8 ah, am;                                                              \
        decomp8(A0, A1, ah, am);                                                   \
        _Pragma("unroll")                                                          \
        for (int nt = 0; nt < 4; ++nt) {                                           \
            s16x8 bh = *(const s16x8*)(wb + nt * 1024 + lane * 16);                \
            accM[nt] = __builtin_amdgcn_mfma_f32_16x16x32_bf16(ah, bh, accM[nt], 0, 0, 0); \
            accS[nt] = __builtin_amdgcn_mfma_f32_16x16x32_bf16(am, bh, accS[nt], 0, 0, 0); \
        }                                                                          \
        decomp8(A2, A3, ah, am);                                                   \
        _Pragma("unroll")                                                          \
        for (int nt = 0; nt < 4; ++nt) {                                           \
            s16x8 bh = *(const s16x8*)(wb + 4096 + nt * 1024 + lane * 16);         \
            accM[nt] = __builtin_amdgcn_mfma_f32_16x16x32_bf16(ah, bh, accM[nt], 0, 0, 0); \
            accS[nt] = __builtin_amdgcn_mfma_f32_16x16x32_bf16(am, bh, accS[nt], 0, 0, 0); \
        }                                                                          \
        __syncthreads();  /* drains stage vmcnt; buffers swap safely */            \
    }

    for (int c = 0; c < NCH; c += 2) {
        CHUNK(aA0, aA1, aA2, aA3, aB0, aB1, aB2, aB3, c);
        CHUNK(aB0, aB1, aB2, aB3, aA0, aA1, aA2, aA3, c + 1);
    }
#undef CHUNK

    // ---- epilogue workspace aliases staging buffers (post-barrier safe) ----
    float (*lg)[EXPN + 1] = (float (*)[EXPN + 1])smem;
    float (*red)[EXPN]    = (float (*)[EXPN])(smem + BM * (EXPN + 1) * 4);

    // combine K halves; C/D layout: col=lane&15, row=(lane>>4)*4+reg [m89]
    if (kh == 0) {
        #pragma unroll
        for (int nt = 0; nt < 4; ++nt)
            #pragma unroll
            for (int r = 0; r < 4; ++r)
                lg[mt * 16 + (lane >> 4) * 4 + r][nt * 16 + (lane & 15)]
                    = accM[nt][r] + 0.00390625f * accS[nt][r];
    }
    __syncthreads();
    if (kh == 1) {
        #pragma unroll
        for (int nt = 0; nt < 4; ++nt)
            #pragma unroll
            for (int r = 0; r < 4; ++r)
                lg[mt * 16 + (lane >> 4) * 4 + r][nt * 16 + (lane & 15)]
                    += accM[nt][r] + 0.00390625f * accS[nt][r];
    }
    __syncthreads();

    // ---- per-row epilogue: 8 waves x 8 rows (proven R1-R9) ----
    float* out_idx   = out;
    float* out_w     = out + 2 * GS;
    float* out_probs = out + 4 * GS + 1;

    const float blane = bias[lane];
    float impL = 0.f, cntL = 0.f;

    for (int rr = 0; rr < 8; ++rr) {
        const int r = (wv << 3) + rr;
        const size_t row = (size_t)row0 + r;
        float v = lg[r][lane] + blane + noise[row * EXPN + lane];

        float m = v;
        #pragma unroll
        for (int off = 32; off >= 1; off >>= 1)
            m = fmaxf(m, __shfl_xor(m, off));
        float e = expf(v - m);
        float s = e;
        #pragma unroll
        for (int off = 32; off >= 1; off >>= 1)
            s += __shfl_xor(s, off);
        float p = e / s;

        out_probs[row * EXPN + lane] = p;
        impL += p;
        cntL += (p > 0.f) ? 1.f : 0.f;

        float v1 = p; int i1 = lane;
        #pragma unroll
        for (int off = 32; off >= 1; off >>= 1) {
            float ov = __shfl_xor(v1, off);
            int   oi = __shfl_xor(i1, off);
            if (ov > v1 || (ov == v1 && oi < i1)) { v1 = ov; i1 = oi; }
        }
        float v2 = (lane == i1) ? -1.f : p; int i2 = lane;
        #pragma unroll
        for (int off = 32; off >= 1; off >>= 1) {
            float ov = __shfl_xor(v2, off);
            int   oi = __shfl_xor(i2, off);
            if (ov > v2 || (ov == v2 && oi < i2)) { v2 = ov; i2 = oi; }
        }
        if (lane == 0) {
            float denom = v1 + v2 + 1e-9f;
            out_idx[row * 2 + 0] = (float)i1;
            out_idx[row * 2 + 1] = (float)i2;
            out_w[row * 2 + 0] = v1 / denom;
            out_w[row * 2 + 1] = v2 / denom;
        }
    }

    red[wv][lane]     = impL;
    red[8 + wv][lane] = cntL;
    __syncthreads();
    if (tid < EXPN) {
        float t1 = 0.f, t2 = 0.f;
        #pragma unroll
        for (int w = 0; w < 8; ++w) { t1 += red[w][tid]; t2 += red[8 + w][tid]; }
        atomicAdd(&ws[tid], t1);
        atomicAdd(&ws[EXPN + tid], t2);
    }
}

__global__ void aux_kernel(const float* __restrict__ ws, float* __restrict__ out)
{
    const int lane = threadIdx.x;  // 64 threads
    float x = ws[lane] * ws[EXPN + lane];   // importance * load
    float s = x;
    #pragma unroll
    for (int off = 32; off >= 1; off >>= 1)
        s += __shfl_xor(s, off);
    float mean = s * (1.f / 64.f);
    float d = x - mean;
    float ss = d * d;
    #pragma unroll
    for (int off = 32; off >= 1; off >>= 1)
        ss += __shfl_xor(ss, off);
    if (lane == 0)
        out[4 * GS] = 0.01f * (ss / 63.f);   // unbiased var * 0.01
}

extern "C" void kernel_launch(void* const* d_in, const int* in_sizes, int n_in,
                              void* d_out, int out_size, void* d_ws, size_t ws_size,
                              hipStream_t stream)
{
    const float* tokens = (const float*)d_in[0];
    const float* noise  = (const float*)d_in[1];
    const float* W      = (const float*)d_in[2];
    const float* bias   = (const float*)d_in[3];
    float* out = (float*)d_out;
    float* ws  = (float*)d_ws;

    // ws layout: [0..127] f32 imp/cnt accumulators | WhF (256KB)
    short* WhF = (short*)(ws + 128);

    prep_kernel<<<EXPN * HID / 8 / 256, 256, 0, stream>>>(W, WhF, ws);
    router_kernel<<<GS / BM, 512, 0, stream>>>(tokens, noise, bias, WhF,
                                               out, ws);
    aux_kernel<<<1, 64, 0, stream>>>(ws, out);
}